// Round 6
// baseline (152.208 us; speedup 1.0000x reference)
//
#include <hip/hip_runtime.h>
#include <hip/hip_bf16.h>

// Problem constants
#define BATCH 32
#define LTOT 4096
#define CCH 64
#define NFFT 16
#define HOP 4
#define NF 9            // n_fft/2+1
#define T_FR 1025       // 1 + L/HOP
#define T_ROWS 1032     // padded rows in mag workspace (rows >= 1025 zeroed)
#define ICH 576         // C * NF
#define OCH 512
#define TY 1023         // conv output length
#define OUTW 128

typedef __attribute__((ext_vector_type(8))) _Float16 half8;
typedef __attribute__((ext_vector_type(4))) float floatx4;
typedef __attribute__((ext_vector_type(16))) float floatx16;

// cos/sin(n*pi/8) for n = 0..15 — compile-time twiddles.
__device__ constexpr float C16[16] = {
    1.0f,  0.923879533f,  0.707106781f,  0.382683432f,  0.0f, -0.382683432f,
   -0.707106781f, -0.923879533f, -1.0f, -0.923879533f, -0.707106781f,
   -0.382683432f,  0.0f,  0.382683432f,  0.707106781f,  0.923879533f};
__device__ constexpr float S16[16] = {
    0.0f,  0.382683432f,  0.707106781f,  0.923879533f,  1.0f,  0.923879533f,
    0.707106781f,  0.382683432f,  0.0f, -0.382683432f, -0.707106781f,
   -0.923879533f, -1.0f, -0.923879533f, -0.707106781f, -0.382683432f};

#define BM 128
#define BN 256   // tile surface measured: BN=128 -> 57.6us, 192 -> 68.4us
                 // (FETCH 94MB: XCD scatter + over-read), 256 -> 55.3us. Keep 256.
#define BK 64

__device__ __forceinline__ void async_copy16(const _Float16* g, _Float16* l) {
  __builtin_amdgcn_global_load_lds(
      (const __attribute__((address_space(1))) unsigned int*)g,
      (__attribute__((address_space(3))) unsigned int*)l, 16, 0, 0);
}

// ---------------------------------------------------------------------------
// Kernel 1: STFT magnitude + weight repack (merged).
// x [B,L,C] fp32 -> m_ws [b][t][f*64+c] fp16 (f-major i-permutation, shared
// with the weight repack so the conv reduction is a pure GEMM over i).
// R19: float4 staging (null vs scalar — kept: fewer instructions, no cost).
// block = 256 = 64 c x 4 t; grid = (258 t-tiles, 32 b).
// ---------------------------------------------------------------------------
__global__ __launch_bounds__(256) void stft_wrepack_kernel(
    const float* __restrict__ x, const float* __restrict__ weight,
    _Float16* __restrict__ m_ws, _Float16* __restrict__ wk) {
  const int b = blockIdx.y;
  const int t0 = blockIdx.x * 4;
  const int tid = threadIdx.x;

  // ---- weight repack slice (independent of stft work) ----
  const int gid = (b * 258 + blockIdx.x) * 256 + tid;
  if (gid < OCH * ICH) {
    int o = gid / ICH, i = gid - o * ICH;
    int c = i / 9, f = i - c * 9;
    const float* src = weight + (size_t)o * (ICH * 3) + i * 3;
    const size_t dst = (size_t)o * ICH + f * 64 + c;
#pragma unroll
    for (int k = 0; k < 3; ++k)
      wk[(size_t)k * OCH * ICH + dst] = (_Float16)src[k];
  }

  // ---- stft tile ----
  __shared__ float xs[28 * 64];   // frames for 4 t: 4*4+12 = 28 rows of x
  const int l0 = t0 * HOP - 8;
  const float* xb = x + (size_t)b * LTOT * CCH;
  // float4 staging: 28 rows x 16 float4 cols = 448 units, 2 x 256 slots.
#pragma unroll
  for (int it = 0; it < 2; ++it) {
    int e = it * 256 + tid;
    int r = e >> 4, c4 = e & 15;
    if (r < 28) {
      int l = l0 + r;
      if (l < 0) l = -l;
      if (l >= LTOT) l = 2 * LTOT - 2 - l;
      *(floatx4*)(&xs[r * 64 + c4 * 4]) =
          *(const floatx4*)(&xb[(size_t)l * CCH + c4 * 4]);
    }
  }
  __syncthreads();

  const int c = tid & 63, tq = tid >> 6;
  const int t = t0 + tq;    // t <= 1031 < T_ROWS
  _Float16* o_ptr = m_ws + ((size_t)b * T_ROWS + t) * ICH + c;
  if (t >= T_FR) {
#pragma unroll
    for (int f = 0; f < NF; ++f) o_ptr[f * 64] = (_Float16)0.0f;
    return;
  }
  float wx[16];
#pragma unroll
  for (int j = 0; j < 16; ++j)
    wx[j] = xs[(tq * 4 + j) * 64 + c] * (0.5f * (1.0f - C16[j]));
  float s[8], d[8];
#pragma unroll
  for (int j = 1; j < 8; ++j) {
    s[j] = wx[j] + wx[16 - j];
    d[j] = wx[j] - wx[16 - j];
  }
#pragma unroll
  for (int f = 0; f < NF; ++f) {
    float re = wx[0] + ((f & 1) ? -wx[8] : wx[8]);
    float im = 0.0f;
#pragma unroll
    for (int j = 1; j < 8; ++j) {
      re += s[j] * C16[(f * j) & 15];
      im += d[j] * S16[(f * j) & 15];
    }
    o_ptr[f * 64] = (_Float16)sqrtf(re * re + im * im);
  }
}

// ---------------------------------------------------------------------------
// Kernel 2 (R20): conv-as-GEMM, 128(o) x 256(t) tile, R13/R15 structure,
// MFMA shape switched 16x16x32 -> 32x32x16 f16.
//   y[b][t][o] = sum_k sum_i wk[k][o][i] * m[b][t+k][i]
// Rationale: sum-of-pipes model (R16-R18: conv time == matrix + LDS-read +
// VALU cycles serialized; schedules can't overlap them) -> shrink the
// matrix pipe itself.  32x32x16 = 4061 FLOP/cyc vs 16x16x32's ~3378
// (m119/m06): 67.8k -> 56.4k cyc/CU for the same 58.6 GFLOP, MFMA inst
// count halved.  Traffic-neutral: LDS bytes/wave-step = (Wo+Wt)*BK
// independent of fragment shape (still 24 ds_read_b128); bank distribution
// under the existing XOR swizzle stays uniform (8 lanes per 4-bank group,
// jj = ks*2 + (lane>>5), slot = jj ^ (row&7)).  acc = 2x4 x f32x16 = 128
// AGPR (unchanged); fragment VGPRs halve (24 vs 48).
// C/D layout (m74/m101, dtype-indep): col=lane&31,
// row=(reg&3)+8*(reg>>2)+4*(lane>>5).  First operand = t-fragment =>
// D row = t, D col = o.
// + R15 XCD-aware remap (4 o-tiles sharing a B-tile on one XCD's L2).
// NOTE (R5): no per-element atomics in epilogue (2.3x regression).
// NOTE (R9): no cooperative grid.sync fusion (3.7x regression).
// NOTE (R10): A must go through LDS via async DMA — direct L2 reads thrash
// the 4 MB XCD L2 (WRITE 45->112 MB, MfmaUtil 44->15%).
// NOTE (R16/R17/R18): schedule arc CLOSED — dbuf 1-block/CU pipeline
// (63.2), counted-vmcnt/raw-barrier/setprio (64.5), 4x128-thread blocks
// (59.5) all <= this config; 2 independent 4-wave blocks/CU is the best
// measured de-phasing.
// grid = 512 linear blocks, block 256 (4 waves, 2(o) x 2(t-half)).
// ---------------------------------------------------------------------------
__global__ __launch_bounds__(256, 2) void conv_gemm_kernel(
    const _Float16* __restrict__ m_ws, const _Float16* __restrict__ wk,
    _Float16* __restrict__ y) {
  // XCD-aware remap of linear ID -> (t-tile, o-tile, batch)
  const int lid = blockIdx.x;            // 0..511
  const int xcd = lid & 7;
  const int rest = lid >> 3;             // 0..63
  const int m = rest & 3;                // o-tile member 0..3
  const int gg = rest >> 2;              // 0..15
  const int g = xcd + 8 * gg;            // B-tile group 0..127 = (t,b)
  const int b = g >> 2;
  const int o0 = m * BM;
  const int t0 = (g & 3) * BN;

  const int tid = threadIdx.x;
  const int wave = tid >> 6, lane = tid & 63;
  const int wm = wave >> 1, wn = wave & 1;     // 2x2 wave grid (o x t-half)

  __shared__ _Float16 as[BM * BK];        // 16 KB    (A: weights, tap-current)
  __shared__ _Float16 bs[(BN + 2) * BK];  // 32.25 KB (B: mag rows t0..t0+257)

  floatx16 acc[2][4];
#pragma unroll
  for (int mt = 0; mt < 2; ++mt)
#pragma unroll
    for (int nt = 0; nt < 4; ++nt)
      acc[mt][nt] = (floatx16)0.0f;

  const _Float16* mb = m_ws + (size_t)b * T_ROWS * ICH;
  const int l31 = lane & 31;             // fragment row (t or o)
  const int h = lane >> 5;               // k half-group
  const int l7 = lane & 7;
  const int srow = lane >> 3;
  const int ssrc_off = srow * ICH + (l7 ^ srow) * 8;

  for (int ib = 0; ib < 9; ++ib) {
    const int i0 = ib * 64;
    const _Float16* bg = mb + (size_t)t0 * ICH + i0;

    // stage B rows t0 .. t0+257 (32 full 8-row segments + one 2-row partial)
#pragma unroll
    for (int it = 0; it < 8; ++it) {
      const int seg = wave * 8 + it;
      async_copy16(bg + (size_t)(seg * 8) * ICH + ssrc_off, &bs[seg * 512]);
    }
    if (tid < 16)   // rows 256,257 (t0 max 768 -> row 1025 < T_ROWS)
      async_copy16(bg + (size_t)256 * ICH + ssrc_off, &bs[256 * 64]);

#pragma unroll
    for (int ksh = 0; ksh < 3; ++ksh) {
      // stage A (weights for tap ksh)
      const _Float16* ag = wk + ((size_t)ksh * OCH + o0) * ICH + i0;
#pragma unroll
      for (int it = 0; it < 4; ++it) {
        const int seg = wave * 4 + it;
        async_copy16(ag + (size_t)(seg * 8) * ICH + ssrc_off, &as[seg * 512]);
      }
      __syncthreads();   // drains vmcnt (B once per ib + A) + barrier

      const int rbB = (l7 + ksh) & 7;    // B read-row low bits (tap-shifted)
#pragma unroll
      for (int ks = 0; ks < 4; ++ks) {   // 4 k-slices of 16 within BK=64
        const int jj = ks * 2 + h;       // 8-half slot index in source row
        const int coffA = ((jj ^ l7) << 3);
        const int coffB = ((jj ^ rbB) << 3);
        half8 af[2], bf[4];
#pragma unroll
        for (int mt = 0; mt < 2; ++mt)
          af[mt] =
              *(const half8*)(&as[(wm * 64 + mt * 32 + l31) * 64 + coffA]);
#pragma unroll
        for (int nt = 0; nt < 4; ++nt)
          bf[nt] = *(const half8*)(
              &bs[(wn * 128 + nt * 32 + l31 + ksh) * 64 + coffB]);
        // first operand = t-fragment => D row = t, D col = o
#pragma unroll
        for (int mt = 0; mt < 2; ++mt)
#pragma unroll
          for (int nt = 0; nt < 4; ++nt)
            acc[mt][nt] = __builtin_amdgcn_mfma_f32_32x32x16_f16(
                bf[nt], af[mt], acc[mt][nt], 0, 0, 0);
      }
      __syncthreads();
    }
  }

  // epilogue: y[b][t][o] fp16, t padded to 1024 rows of OCH halves.
  // 32x32 C layout: t = (reg&3) + 8*(reg>>2) + 4*h (+ tile bases),
  // o = l31 (+ tile bases).  Inner mt loop: mt=0,1 write 64 B each,
  // adjacent in o and program order -> 128 B contiguous per t-row per wave
  // (L2 write-combine, R13 pattern preserved).
  _Float16* yb = y + (((size_t)b << 10)) * OCH;
#pragma unroll
  for (int nt = 0; nt < 4; ++nt) {
    const int tb = t0 + wn * 128 + nt * 32 + h * 4;
#pragma unroll
    for (int rg = 0; rg < 16; ++rg) {
      const int t = tb + (rg & 3) + 8 * (rg >> 2);
      if (t < TY) {
#pragma unroll
        for (int mt = 0; mt < 2; ++mt) {
          const int o = o0 + wm * 64 + mt * 32 + l31;
          yb[(size_t)t * OCH + o] = (_Float16)acc[mt][nt][rg];
        }
      }
    }
  }
}

// ---------------------------------------------------------------------------
// Kernel 3: adaptive avg pool (overlapping torch bins) + bias, half8 wide.
// out[b][w][o] = bias[o] + mean_{t in bin(w)} y[b][t][o]
// one (b, w, o-octet) per thread: 32*128*64 = 262144 = 1024 blocks x 256.
// ---------------------------------------------------------------------------
__global__ __launch_bounds__(256) void pool_kernel(const _Float16* __restrict__ y,
                                                   const float* __restrict__ bias,
                                                   float* __restrict__ out) {
  const int unit = blockIdx.x * 256 + threadIdx.x;
  const int b = unit >> 13;
  const int w = (unit >> 6) & 127;
  const int o = (unit & 63) * 8;
  const int start = (w * TY) >> 7;
  const int end = ((w + 1) * TY + 127) >> 7;
  const _Float16* yb = y + (((size_t)b << 10)) * OCH;
  float s[8];
#pragma unroll
  for (int i = 0; i < 8; ++i) s[i] = 0.0f;
  for (int t = start; t < end; ++t) {
    half8 v = *(const half8*)(yb + (size_t)t * OCH + o);
#pragma unroll
    for (int i = 0; i < 8; ++i) s[i] += (float)v[i];
  }
  const float inv = 1.0f / (float)(end - start);
  float* op = out + ((size_t)b * OUTW + w) * OCH + o;
  floatx4 r0, r1;
#pragma unroll
  for (int i = 0; i < 4; ++i) r0[i] = s[i] * inv + bias[o + i];
#pragma unroll
  for (int i = 0; i < 4; ++i) r1[i] = s[4 + i] * inv + bias[o + 4 + i];
  *(floatx4*)(op) = r0;
  *(floatx4*)(op + 4) = r1;
}

// ---------------------------------------------------------------------------
extern "C" void kernel_launch(void* const* d_in, const int* in_sizes, int n_in,
                              void* d_out, int out_size, void* d_ws, size_t ws_size,
                              hipStream_t stream) {
  const float* x = (const float*)d_in[0];       // [32, 4096, 64]
  const float* weight = (const float*)d_in[1];  // [512, 576, 3]
  const float* bias = (const float*)d_in[2];    // [512]
  float* out = (float*)d_out;                   // [32, 128, 512]

  char* ws = (char*)d_ws;
  const size_t m_bytes = (size_t)BATCH * T_ROWS * ICH * sizeof(_Float16);  // 38,043,648
  const size_t w_bytes = (size_t)3 * OCH * ICH * sizeof(_Float16);         // 1,769,472
  _Float16* m_ws = (_Float16*)ws;
  _Float16* wk = (_Float16*)(ws + m_bytes);
  _Float16* y = (_Float16*)(ws + m_bytes + w_bytes);  // [32][1024][512] fp16

  hipLaunchKernelGGL(stft_wrepack_kernel, dim3(258, BATCH), dim3(256), 0,
                     stream, x, weight, m_ws, wk);
  hipLaunchKernelGGL(conv_gemm_kernel, dim3(512), dim3(256), 0, stream,
                     m_ws, wk, y);
  hipLaunchKernelGGL(pool_kernel, dim3(OUTW * BATCH / 4), dim3(256), 0, stream,
                     y, bias, out);
}

// Round 7
// 151.922 us; speedup vs baseline: 1.0019x; 1.0019x over previous
//
#include <hip/hip_runtime.h>
#include <hip/hip_bf16.h>

// Problem constants
#define BATCH 32
#define LTOT 4096
#define CCH 64
#define NFFT 16
#define HOP 4
#define NF 9            // n_fft/2+1
#define T_FR 1025       // 1 + L/HOP
#define T_ROWS 1032     // padded rows in mag workspace (rows >= 1025 zeroed)
#define ICH 576         // C * NF
#define OCH 512
#define TY 1023         // conv output length
#define OUTW 128

typedef __attribute__((ext_vector_type(8))) _Float16 half8;
typedef __attribute__((ext_vector_type(4))) float floatx4;

// cos/sin(n*pi/8) for n = 0..15 — compile-time twiddles.
__device__ constexpr float C16[16] = {
    1.0f,  0.923879533f,  0.707106781f,  0.382683432f,  0.0f, -0.382683432f,
   -0.707106781f, -0.923879533f, -1.0f, -0.923879533f, -0.707106781f,
   -0.382683432f,  0.0f,  0.382683432f,  0.707106781f,  0.923879533f};
__device__ constexpr float S16[16] = {
    0.0f,  0.382683432f,  0.707106781f,  0.923879533f,  1.0f,  0.923879533f,
    0.707106781f,  0.382683432f,  0.0f, -0.382683432f, -0.707106781f,
   -0.923879533f, -1.0f, -0.923879533f, -0.707106781f, -0.382683432f};

#define BM 128
#define BN 256
#define BK 64

__device__ __forceinline__ void async_copy16(const _Float16* g, _Float16* l) {
  __builtin_amdgcn_global_load_lds(
      (const __attribute__((address_space(1))) unsigned int*)g,
      (__attribute__((address_space(3))) unsigned int*)l, 16, 0, 0);
}

// ---------------------------------------------------------------------------
// Kernel 1: STFT magnitude + weight repack (merged).  (unchanged)
// ---------------------------------------------------------------------------
__global__ __launch_bounds__(256) void stft_wrepack_kernel(
    const float* __restrict__ x, const float* __restrict__ weight,
    _Float16* __restrict__ m_ws, _Float16* __restrict__ wk) {
  const int b = blockIdx.y;
  const int t0 = blockIdx.x * 4;
  const int tid = threadIdx.x;

  // ---- weight repack slice (independent of stft work) ----
  const int gid = (b * 258 + blockIdx.x) * 256 + tid;
  if (gid < OCH * ICH) {
    int o = gid / ICH, i = gid - o * ICH;
    int c = i / 9, f = i - c * 9;
    const float* src = weight + (size_t)o * (ICH * 3) + i * 3;
    const size_t dst = (size_t)o * ICH + f * 64 + c;
#pragma unroll
    for (int k = 0; k < 3; ++k)
      wk[(size_t)k * OCH * ICH + dst] = (_Float16)src[k];
  }

  // ---- stft tile ----
  __shared__ float xs[28 * 64];   // frames for 4 t: 4*4+12 = 28 rows of x
  const int l0 = t0 * HOP - 8;
  const float* xb = x + (size_t)b * LTOT * CCH;
#pragma unroll
  for (int it = 0; it < 2; ++it) {
    int e = it * 256 + tid;
    int r = e >> 4, c4 = e & 15;
    if (r < 28) {
      int l = l0 + r;
      if (l < 0) l = -l;
      if (l >= LTOT) l = 2 * LTOT - 2 - l;
      *(floatx4*)(&xs[r * 64 + c4 * 4]) =
          *(const floatx4*)(&xb[(size_t)l * CCH + c4 * 4]);
    }
  }
  __syncthreads();

  const int c = tid & 63, tq = tid >> 6;
  const int t = t0 + tq;    // t <= 1031 < T_ROWS
  _Float16* o_ptr = m_ws + ((size_t)b * T_ROWS + t) * ICH + c;
  if (t >= T_FR) {
#pragma unroll
    for (int f = 0; f < NF; ++f) o_ptr[f * 64] = (_Float16)0.0f;
    return;
  }
  float wx[16];
#pragma unroll
  for (int j = 0; j < 16; ++j)
    wx[j] = xs[(tq * 4 + j) * 64 + c] * (0.5f * (1.0f - C16[j]));
  float s[8], d[8];
#pragma unroll
  for (int j = 1; j < 8; ++j) {
    s[j] = wx[j] + wx[16 - j];
    d[j] = wx[j] - wx[16 - j];
  }
#pragma unroll
  for (int f = 0; f < NF; ++f) {
    float re = wx[0] + ((f & 1) ? -wx[8] : wx[8]);
    float im = 0.0f;
#pragma unroll
    for (int j = 1; j < 8; ++j) {
      re += s[j] * C16[(f * j) & 15];
      im += d[j] * S16[(f * j) & 15];
    }
    o_ptr[f * 64] = (_Float16)sqrtf(re * re + im * im);
  }
}

// ---------------------------------------------------------------------------
// Kernel 2 (R21): conv-as-GEMM 128(o)x256(t), R13/R15 16x16x32 loop verbatim
// (R20's 32x32 shape: 5.3M bank conflicts = 4 cyc/read; empirical rule —
// this staging swizzle is conflict-free only with 16-row fragments), with
// the adaptive-pool FUSED into the epilogue (y workspace deleted):
//   - acc -> LDS fp16 tile yt[256][132] (arena unioned with as/bs, 67.6 KB,
//     still 2 blocks/CU).  Same fp16 rounding as the old y path.
//   - bins fully inside this block's t-range: fp32 sum over yt rows, /count,
//     +bias, direct store to out.  Ownership: bin w belongs to the t-tile
//     containing start(w) -> tiles own {33,32,32,31} bins.
//   - 3 straddle bins (w=32,64,96; 1 left row + 8 right rows, count 9):
//     both neighbors write fp32 partials to a ws side-buffer (write-only,
//     no ordering assumption, no atomics); edge_kernel combines.
// Saves pool's 33.5MB y read + 33.5MB y write + a kernel launch.
// NOTE (R5): no per-element atomics (2.3x).  NOTE (R9): no grid.sync (3.7x).
// NOTE (R10): A via LDS async DMA only.  NOTE (R16-R18): schedule arc closed.
// grid = 512 linear blocks, block 256 (4 waves, 2(o) x 2(t-half)).
// ---------------------------------------------------------------------------
__global__ __launch_bounds__(256, 2) void conv_fused_kernel(
    const _Float16* __restrict__ m_ws, const _Float16* __restrict__ wk,
    const float* __restrict__ bias, float* __restrict__ side,
    float* __restrict__ out) {
  // XCD-aware remap of linear ID -> (t-tile, o-tile, batch)
  const int lid = blockIdx.x;            // 0..511
  const int xcd = lid & 7;
  const int rest = lid >> 3;             // 0..63
  const int m = rest & 3;                // o-tile member 0..3
  const int gg = rest >> 2;              // 0..15
  const int g = xcd + 8 * gg;            // B-tile group 0..127 = (t,b)
  const int b = g >> 2;
  const int tt = g & 3;                  // t-tile index
  const int o0 = m * BM;
  const int t0 = tt * BN;

  const int tid = threadIdx.x;
  const int wave = tid >> 6, lane = tid & 63;
  const int wm = wave >> 1, wn = wave & 1;     // 2x2 wave grid (o x t-half)

  // LDS arena: main loop uses as(16KB)+bs(33KB); epilogue reuses it as
  // yt[256][132] fp16 (67.6KB).  2 x 67.6 = 135 KB <= 160 KB/CU.
  __shared__ _Float16 arena[256 * 132];
  _Float16* as = arena;                  // [BM][BK]
  _Float16* bs = arena + BM * BK;        // [(BN+2)][BK]
  _Float16* yt = arena;                  // [256][132] (epilogue)

  floatx4 acc[4][8];
#pragma unroll
  for (int mt = 0; mt < 4; ++mt)
#pragma unroll
    for (int nt = 0; nt < 8; ++nt)
      acc[mt][nt] = (floatx4)0.0f;

  const _Float16* mb = m_ws + (size_t)b * T_ROWS * ICH;
  const int frow = lane & 15;
  const int quad = lane >> 4;
  const int l7 = lane & 7;
  const int srow = lane >> 3;
  const int ssrc_off = srow * ICH + (l7 ^ srow) * 8;

  for (int ib = 0; ib < 9; ++ib) {
    const int i0 = ib * 64;
    const _Float16* bg = mb + (size_t)t0 * ICH + i0;

    // stage B rows t0 .. t0+257 (32 full 8-row segments + one 2-row partial)
#pragma unroll
    for (int it = 0; it < 8; ++it) {
      const int seg = wave * 8 + it;
      async_copy16(bg + (size_t)(seg * 8) * ICH + ssrc_off, &bs[seg * 512]);
    }
    if (tid < 16)   // rows 256,257 (t0 max 768 -> row 1025 < T_ROWS)
      async_copy16(bg + (size_t)256 * ICH + ssrc_off, &bs[256 * 64]);

#pragma unroll
    for (int ksh = 0; ksh < 3; ++ksh) {
      // stage A (weights for tap ksh)
      const _Float16* ag = wk + ((size_t)ksh * OCH + o0) * ICH + i0;
#pragma unroll
      for (int it = 0; it < 4; ++it) {
        const int seg = wave * 4 + it;
        async_copy16(ag + (size_t)(seg * 8) * ICH + ssrc_off, &as[seg * 512]);
      }
      __syncthreads();   // drains vmcnt (B once per ib + A) + barrier

      const int rb7 = (frow + ksh) & 7;
#pragma unroll
      for (int kk2 = 0; kk2 < 2; ++kk2) {
        const int jj = kk2 * 4 + quad;
        const int coffA = ((jj ^ l7) << 3);
        const int coffB = ((jj ^ rb7) << 3);
        half8 af[4], bf[8];
#pragma unroll
        for (int mt = 0; mt < 4; ++mt)
          af[mt] = *(const half8*)(&as[(wm * 64 + mt * 16 + frow) * 64 + coffA]);
#pragma unroll
        for (int nt = 0; nt < 8; ++nt)
          bf[nt] = *(const half8*)(
              &bs[(wn * 128 + nt * 16 + frow + ksh) * 64 + coffB]);
        // first operand = t-fragment => D row (quad*4+reg) = t, D col = o
#pragma unroll
        for (int mt = 0; mt < 4; ++mt)
#pragma unroll
          for (int nt = 0; nt < 8; ++nt)
            acc[mt][nt] = __builtin_amdgcn_mfma_f32_16x16x32_f16(
                bf[nt], af[mt], acc[mt][nt], 0, 0, 0);
      }
      __syncthreads();   // also protects arena reuse below on last iter
    }
  }

  // ---- fused epilogue ----
  // Phase 1: acc -> yt[256][132] fp16 (local t x local o, +4 pad halves).
  const int col = lane & 15;
#pragma unroll
  for (int nt = 0; nt < 8; ++nt) {
    const int tl = wn * 128 + nt * 16 + quad * 4;
#pragma unroll
    for (int r = 0; r < 4; ++r) {
#pragma unroll
      for (int mt = 0; mt < 4; ++mt) {
        const int ol = wm * 64 + mt * 16 + col;
        yt[(tl + r) * 132 + ol] = (_Float16)acc[mt][nt][r];
      }
    }
  }
  __syncthreads();

  // Phase 2: pool owned bins.  start(w)=(w*1023)>>7, end=((w+1)*1023+127)>>7.
  // Tile tt owns bins with start in [t0, t0+256): W_FIRST/NB tables below.
  // Last owned bin of tt=0,1,2 straddles (end > t0+256) -> fp32 partial of
  // in-tile rows to side[b][tt][0][o]; tt>=1 writes the 8-row head partial
  // of bin 32*tt to side[b][tt-1][1][o].  Straddle bins have count 9.
  const int W_FIRST[4] = {0, 33, 65, 97};
  const int NB[4] = {33, 32, 32, 31};
  const int wf = W_FIRST[tt], nb = NB[tt];
  const int items = nb * 128;
  for (int idx = tid; idx < items; idx += 256) {
    const int wl = idx >> 7, ol = idx & 127;
    const int w = wf + wl;
    const int s_g = (w * TY) >> 7;
    const int e_g = ((w + 1) * TY + 127) >> 7;
    const bool straddle = (e_g > t0 + 256);
    const int sl = s_g - t0;
    const int el = straddle ? 256 : (e_g - t0);
    float sum = 0.0f;
    for (int t = sl; t < el; ++t) sum += (float)yt[t * 132 + ol];
    if (!straddle) {
      out[((size_t)b * OUTW + w) * OCH + o0 + ol] =
          bias[o0 + ol] + sum * (1.0f / (float)(e_g - s_g));
    } else {
      side[(((size_t)b * 3 + tt) * 2 + 0) * OCH + o0 + ol] = sum;
    }
  }
  if (tt >= 1 && tid < 128) {
    const int ol = tid;
    float sum = 0.0f;
#pragma unroll
    for (int t = 0; t < 8; ++t) sum += (float)yt[t * 132 + ol];
    side[(((size_t)b * 3 + (tt - 1)) * 2 + 1) * OCH + o0 + ol] = sum;
  }
}

// ---------------------------------------------------------------------------
// Kernel 3 (R21): straddle-bin combine.  out[b][32(e+1)][o] =
//   bias[o] + (left_partial + right_partial) / 9   (3 bins x 32 b x 512 o)
// ---------------------------------------------------------------------------
__global__ __launch_bounds__(256) void edge_kernel(
    const float* __restrict__ side, const float* __restrict__ bias,
    float* __restrict__ out) {
  const int gid = blockIdx.x * 256 + threadIdx.x;   // 0..49151
  const int o = gid & 511;
  const int rest = gid >> 9;                        // 0..95
  const int e = rest % 3;
  const int b = rest / 3;
  const int w = 32 * (e + 1);
  const float l = side[(((size_t)b * 3 + e) * 2 + 0) * OCH + o];
  const float r = side[(((size_t)b * 3 + e) * 2 + 1) * OCH + o];
  out[((size_t)b * OUTW + w) * OCH + o] = bias[o] + (l + r) * (1.0f / 9.0f);
}

// ---------------------------------------------------------------------------
extern "C" void kernel_launch(void* const* d_in, const int* in_sizes, int n_in,
                              void* d_out, int out_size, void* d_ws, size_t ws_size,
                              hipStream_t stream) {
  const float* x = (const float*)d_in[0];       // [32, 4096, 64]
  const float* weight = (const float*)d_in[1];  // [512, 576, 3]
  const float* bias = (const float*)d_in[2];    // [512]
  float* out = (float*)d_out;                   // [32, 128, 512]

  char* ws = (char*)d_ws;
  const size_t m_bytes = (size_t)BATCH * T_ROWS * ICH * sizeof(_Float16);  // 38,043,648
  const size_t w_bytes = (size_t)3 * OCH * ICH * sizeof(_Float16);         // 1,769,472
  _Float16* m_ws = (_Float16*)ws;
  _Float16* wk = (_Float16*)(ws + m_bytes);
  float* side = (float*)(ws + m_bytes + w_bytes);  // [32][3][2][512] fp32

  hipLaunchKernelGGL(stft_wrepack_kernel, dim3(258, BATCH), dim3(256), 0,
                     stream, x, weight, m_ws, wk);
  hipLaunchKernelGGL(conv_fused_kernel, dim3(512), dim3(256), 0, stream,
                     m_ws, wk, bias, side, out);
  hipLaunchKernelGGL(edge_kernel, dim3(192), dim3(256), 0, stream,
                     side, bias, out);
}

// Round 8
// 127.672 us; speedup vs baseline: 1.1922x; 1.1899x over previous
//
#include <hip/hip_runtime.h>
#include <hip/hip_bf16.h>

// Problem constants
#define BATCH 32
#define LTOT 4096
#define CCH 64
#define NFFT 16
#define HOP 4
#define NF 9            // n_fft/2+1
#define T_FR 1025       // 1 + L/HOP
#define T_ROWS 1032     // padded rows in mag workspace (rows >= 1025 zeroed)
#define ICH 576         // C * NF
#define OCH 512
#define TY 1023         // conv output length
#define OUTW 128
#define KTOT 1728       // 3 taps x 576

typedef __attribute__((ext_vector_type(8))) _Float16 half8;
typedef __attribute__((ext_vector_type(4))) float floatx4;

// cos/sin(n*pi/8) for n = 0..15 — compile-time twiddles.
__device__ constexpr float C16[16] = {
    1.0f,  0.923879533f,  0.707106781f,  0.382683432f,  0.0f, -0.382683432f,
   -0.707106781f, -0.923879533f, -1.0f, -0.923879533f, -0.707106781f,
   -0.382683432f,  0.0f,  0.382683432f,  0.707106781f,  0.923879533f};
__device__ constexpr float S16[16] = {
    0.0f,  0.382683432f,  0.707106781f,  0.923879533f,  1.0f,  0.923879533f,
    0.707106781f,  0.382683432f,  0.0f, -0.382683432f, -0.707106781f,
   -0.923879533f, -1.0f, -0.923879533f, -0.707106781f, -0.382683432f};

__device__ __forceinline__ void async_copy16(const _Float16* g, _Float16* l) {
  __builtin_amdgcn_global_load_lds(
      (const __attribute__((address_space(1))) unsigned int*)g,
      (__attribute__((address_space(3))) unsigned int*)l, 16, 0, 0);
}

// ---------------------------------------------------------------------------
// Kernel 1: STFT magnitude + weight repack.
// x [B,L,C] fp32 -> m_ws [b][t][f*64+c] fp16.
// R22 repack: wkr[o][kappa], kappa = k*576 + f*64 + c (contiguous K=1728
// matching pmean layout, so the conv+pool collapses to one pure GEMM).
// ---------------------------------------------------------------------------
__global__ __launch_bounds__(256) void stft_wrepack_kernel(
    const float* __restrict__ x, const float* __restrict__ weight,
    _Float16* __restrict__ m_ws, _Float16* __restrict__ wkr) {
  const int b = blockIdx.y;
  const int t0 = blockIdx.x * 4;
  const int tid = threadIdx.x;

  // ---- weight repack slice (independent of stft work) ----
  const int gid = (b * 258 + blockIdx.x) * 256 + tid;
  if (gid < OCH * ICH) {
    int o = gid / ICH, i = gid - o * ICH;
    int c = i / 9, f = i - c * 9;
    const float* src = weight + (size_t)o * (ICH * 3) + i * 3;
    _Float16* dst = wkr + (size_t)o * KTOT + f * 64 + c;
#pragma unroll
    for (int k = 0; k < 3; ++k)
      dst[k * ICH] = (_Float16)src[k];
  }

  // ---- stft tile ----
  __shared__ float xs[28 * 64];   // frames for 4 t: 4*4+12 = 28 rows of x
  const int l0 = t0 * HOP - 8;
  const float* xb = x + (size_t)b * LTOT * CCH;
#pragma unroll
  for (int it = 0; it < 2; ++it) {
    int e = it * 256 + tid;
    int r = e >> 4, c4 = e & 15;
    if (r < 28) {
      int l = l0 + r;
      if (l < 0) l = -l;
      if (l >= LTOT) l = 2 * LTOT - 2 - l;
      *(floatx4*)(&xs[r * 64 + c4 * 4]) =
          *(const floatx4*)(&xb[(size_t)l * CCH + c4 * 4]);
    }
  }
  __syncthreads();

  const int c = tid & 63, tq = tid >> 6;
  const int t = t0 + tq;    // t <= 1031 < T_ROWS
  _Float16* o_ptr = m_ws + ((size_t)b * T_ROWS + t) * ICH + c;
  if (t >= T_FR) {
#pragma unroll
    for (int f = 0; f < NF; ++f) o_ptr[f * 64] = (_Float16)0.0f;
    return;
  }
  float wx[16];
#pragma unroll
  for (int j = 0; j < 16; ++j)
    wx[j] = xs[(tq * 4 + j) * 64 + c] * (0.5f * (1.0f - C16[j]));
  float s[8], d[8];
#pragma unroll
  for (int j = 1; j < 8; ++j) {
    s[j] = wx[j] + wx[16 - j];
    d[j] = wx[j] - wx[16 - j];
  }
#pragma unroll
  for (int f = 0; f < NF; ++f) {
    float re = wx[0] + ((f & 1) ? -wx[8] : wx[8]);
    float im = 0.0f;
#pragma unroll
    for (int j = 1; j < 8; ++j) {
      re += s[j] * C16[(f * j) & 15];
      im += d[j] * S16[(f * j) & 15];
    }
    o_ptr[f * 64] = (_Float16)sqrtf(re * re + im * im);
  }
}

// ---------------------------------------------------------------------------
// Kernel 2 (R22): pre-pool the magnitudes.  Pool and conv are both linear
// in t, so they commute: pooling FIRST shrinks the GEMM t-dim 1023 -> 128
// (58.6 -> 7.25 GFLOP).  pmean[b][w][kappa], kappa = k*576+i:
//   pmean = (1/cnt_w) * sum_{t in [s_w, e_w)} m[b][t+k][i]
// (bin tables exactly match torch adaptive_avg_pool1d; t+k <= 1024 < T_FR.)
// Mean (not sum) keeps fp16 rounding at the same relative scale as m itself.
// block 256 (216 active: 3 k x 72 i-octets), one block per (w, b).
// ---------------------------------------------------------------------------
__global__ __launch_bounds__(256) void pmean_kernel(
    const _Float16* __restrict__ m_ws, _Float16* __restrict__ pm) {
  const int w = blockIdx.x, b = blockIdx.y;
  const int j = threadIdx.x;
  if (j >= 216) return;
  const int k = j / 72;                  // tap 0..2
  const int i8 = (j - k * 72) * 8;       // i-octet base
  const int s = (w * TY) >> 7;
  const int e = ((w + 1) * TY + 127) >> 7;
  const int cnt = e - s;
  const float inv = 1.0f / (float)cnt;
  const _Float16* src =
      m_ws + ((size_t)b * T_ROWS + s + k) * ICH + i8;
  float acc[8];
#pragma unroll
  for (int q = 0; q < 8; ++q) acc[q] = 0.0f;
  for (int t = 0; t < cnt; ++t) {
    half8 v = *(const half8*)(src + (size_t)t * ICH);
#pragma unroll
    for (int q = 0; q < 8; ++q) acc[q] += (float)v[q];
  }
  half8 r;
#pragma unroll
  for (int q = 0; q < 8; ++q) r[q] = (_Float16)(acc[q] * inv);
  *(half8*)(pm + ((size_t)(b * OUTW + w)) * KTOT + j * 8) = r;
}

// ---------------------------------------------------------------------------
// Kernel 3 (R22): the collapsed GEMM.
//   out[b][w][o] = bias[o] + sum_{kappa<1728} wkr[o][kappa]*pmean[b][w][kappa]
// 4096(bw) x 512(o) x 1728 — 8x fewer FLOPs than the old conv GEMM.
// Tile 64(o) x 128(w = one batch), grid 256 = 1 block/CU; fragment +
// staging swizzle machinery verbatim from the proven R13 loop (pure GEMM =
// R13's ksh=0 path; conflict-free 16-row fragments per R20's empirical rule).
// XCD map: all 8 o-tiles of batch b on one XCD -> pm[b] (442 KB) + wkr
// (1.77 MB) are XCD-L2-resident; b = bq*8 + xcd.
// NOTE (R10): operands staged via async DMA -> LDS (direct L2 reads thrash).
// ---------------------------------------------------------------------------
__global__ __launch_bounds__(256, 2) void gemm_pooled_kernel(
    const _Float16* __restrict__ pm, const _Float16* __restrict__ wkr,
    const float* __restrict__ bias, float* __restrict__ out) {
  const int lid = blockIdx.x;            // 0..255
  const int xcd = lid & 7;
  const int rest = lid >> 3;             // 0..31
  const int m8 = rest & 7;               // o-tile 0..7
  const int bq = rest >> 3;              // 0..3
  const int b = bq * 8 + xcd;
  const int o0 = m8 * 64;

  const int tid = threadIdx.x;
  const int wave = tid >> 6, lane = tid & 63;
  const int wm = wave >> 1, wn = wave & 1;   // 2(o) x 2(w) wave grid

  __shared__ _Float16 as[64 * 64];       // 8 KB  (W rows o0..o0+63)
  __shared__ _Float16 bs[128 * 64];      // 16 KB (pmean rows, all w of b)

  floatx4 acc[2][4];
#pragma unroll
  for (int mt = 0; mt < 2; ++mt)
#pragma unroll
    for (int nt = 0; nt < 4; ++nt)
      acc[mt][nt] = (floatx4)0.0f;

  const int frow = lane & 15;
  const int quad = lane >> 4;
  const int l7 = lane & 7;
  const int srow = lane >> 3;
  const int ssrc_off = srow * KTOT + (l7 ^ srow) * 8;

  const _Float16* ab = wkr + (size_t)o0 * KTOT;
  const _Float16* bb = pm + (size_t)b * OUTW * KTOT;

  for (int kb = 0; kb < 27; ++kb) {
    const int i0 = kb * 64;
    // stage A: 8 segs of 8 rows (2 per wave)
#pragma unroll
    for (int it = 0; it < 2; ++it) {
      const int seg = wave * 2 + it;
      async_copy16(ab + (size_t)(seg * 8) * KTOT + i0 + ssrc_off,
                   &as[seg * 512]);
    }
    // stage B: 16 segs of 8 rows (4 per wave)
#pragma unroll
    for (int it = 0; it < 4; ++it) {
      const int seg = wave * 4 + it;
      async_copy16(bb + (size_t)(seg * 8) * KTOT + i0 + ssrc_off,
                   &bs[seg * 512]);
    }
    __syncthreads();   // drains vmcnt + barrier

#pragma unroll
    for (int kk2 = 0; kk2 < 2; ++kk2) {
      const int jj = kk2 * 4 + quad;
      const int coff = ((jj ^ l7) << 3);
      half8 af[2], bf[4];
#pragma unroll
      for (int mt = 0; mt < 2; ++mt)
        af[mt] = *(const half8*)(&as[(wm * 32 + mt * 16 + frow) * 64 + coff]);
#pragma unroll
      for (int nt = 0; nt < 4; ++nt)
        bf[nt] = *(const half8*)(&bs[(wn * 64 + nt * 16 + frow) * 64 + coff]);
      // first operand = w-fragment => D row (quad*4+reg) = w, D col = o
#pragma unroll
      for (int mt = 0; mt < 2; ++mt)
#pragma unroll
        for (int nt = 0; nt < 4; ++nt)
          acc[mt][nt] = __builtin_amdgcn_mfma_f32_16x16x32_f16(
              bf[nt], af[mt], acc[mt][nt], 0, 0, 0);
    }
    __syncthreads();
  }

  // epilogue: out[b][w][o] fp32 = bias + acc.  mt inner => 128 B contiguous
  // per (nt,r) per wave (L2 write-combine pattern).
  const int col = lane & 15;
  float* ob = out + (size_t)b * OUTW * OCH;
#pragma unroll
  for (int nt = 0; nt < 4; ++nt) {
    const int wb = wn * 64 + nt * 16 + quad * 4;
#pragma unroll
    for (int r = 0; r < 4; ++r) {
      const int w = wb + r;
#pragma unroll
      for (int mt = 0; mt < 2; ++mt) {
        const int o = o0 + wm * 32 + mt * 16 + col;
        ob[(size_t)w * OCH + o] = bias[o] + acc[mt][nt][r];
      }
    }
  }
}

// ---------------------------------------------------------------------------
extern "C" void kernel_launch(void* const* d_in, const int* in_sizes, int n_in,
                              void* d_out, int out_size, void* d_ws, size_t ws_size,
                              hipStream_t stream) {
  const float* x = (const float*)d_in[0];       // [32, 4096, 64]
  const float* weight = (const float*)d_in[1];  // [512, 576, 3]
  const float* bias = (const float*)d_in[2];    // [512]
  float* out = (float*)d_out;                   // [32, 128, 512]

  char* ws = (char*)d_ws;
  const size_t m_bytes = (size_t)BATCH * T_ROWS * ICH * sizeof(_Float16);  // 38,043,648
  const size_t w_bytes = (size_t)OCH * KTOT * sizeof(_Float16);            // 1,769,472
  _Float16* m_ws = (_Float16*)ws;
  _Float16* wkr = (_Float16*)(ws + m_bytes);
  _Float16* pm = (_Float16*)(ws + m_bytes + w_bytes);  // [32][128][1728] fp16

  hipLaunchKernelGGL(stft_wrepack_kernel, dim3(258, BATCH), dim3(256), 0,
                     stream, x, weight, m_ws, wkr);
  hipLaunchKernelGGL(pmean_kernel, dim3(OUTW, BATCH), dim3(256), 0, stream,
                     m_ws, pm);
  hipLaunchKernelGGL(gemm_pooled_kernel, dim3(256), dim3(256), 0, stream,
                     pm, wkr, bias, out);
}